// Round 1
// 3558.607 us; speedup vs baseline: 1.3005x; 1.3005x over previous
//
#include <hip/hip_runtime.h>
#include <math.h>
#include <stdint.h>

#define T_SEQ 4096
#define CDIM  1024
#define NL    6
#define NH    16
#define BSZ   64
#define HDIM  64
#define MROWS 16384   // B*T

typedef __bf16 bf16x8 __attribute__((ext_vector_type(8)));
typedef float  f32x4  __attribute__((ext_vector_type(4)));

__device__ __forceinline__ unsigned short f2bf(float f) {
  __bf16 h = (__bf16)f;
  return __builtin_bit_cast(unsigned short, h);
}
__device__ __forceinline__ float bf2f(unsigned short u) {
  unsigned int v = ((unsigned int)u) << 16;
  return __builtin_bit_cast(float, v);
}

// async global->LDS, 16B per lane; lds dest must be wave-uniform (HW adds lane*16)
typedef __attribute__((address_space(3))) unsigned int* lds_u32p;
typedef const __attribute__((address_space(1))) unsigned int* glb_u32p;
__device__ __forceinline__ void glds16(const void* g, void* l) {
  __builtin_amdgcn_global_load_lds((glb_u32p)(uintptr_t)g, (lds_u32p)(uintptr_t)l, 16, 0, 0);
}

// Abramowitz-Stegun 7.1.26, |err| <= 1.5e-7 — invisible at bf16 precision
__device__ __forceinline__ float erf_fast(float x) {
  float ax = fabsf(x);
  float t = __builtin_amdgcn_rcpf(fmaf(0.3275911f, ax, 1.0f));
  float y = t * fmaf(t, fmaf(t, fmaf(t, fmaf(t, 1.061405429f, -1.453152027f),
                                     1.421413741f), -0.284496736f), 0.254829592f);
  float r = 1.0f - y * __expf(-ax * ax);
  return copysignf(r, x);
}
__device__ __forceinline__ float gelu_fast(float v) {
  return 0.5f * v * (1.0f + erf_fast(v * 0.70710678118654752440f));
}

// ---------------- LayerNorm: one block per row; OBF=1 -> bf16 out ------------
template<int OBF>
__global__ __launch_bounds__(256) void ln_kernel(const float* __restrict__ x,
    const float* __restrict__ w, const float* __restrict__ bb, void* __restrict__ out)
{
  int row = blockIdx.x;
  int tid = threadIdx.x;
  float4 v = ((const float4*)(x + (size_t)row * CDIM))[tid];
  float s  = v.x + v.y + v.z + v.w;
  float ss = v.x*v.x + v.y*v.y + v.z*v.z + v.w*v.w;
  #pragma unroll
  for (int o = 32; o > 0; o >>= 1) { s += __shfl_down(s, o); ss += __shfl_down(ss, o); }
  __shared__ float red[8];
  int wid = tid >> 6, lane = tid & 63;
  if (lane == 0) { red[wid] = s; red[4 + wid] = ss; }
  __syncthreads();
  if (tid == 0) {
    red[0] = red[0] + red[1] + red[2] + red[3];
    red[4] = red[4] + red[5] + red[6] + red[7];
  }
  __syncthreads();
  float mean = red[0] * (1.0f / CDIM);
  float var  = red[4] * (1.0f / CDIM) - mean * mean;
  float inv  = 1.0f / sqrtf(var + 1e-5f);
  float4 w4 = ((const float4*)w)[tid];
  float4 b4 = ((const float4*)bb)[tid];
  float4 o4;
  o4.x = (v.x - mean) * inv * w4.x + b4.x;
  o4.y = (v.y - mean) * inv * w4.y + b4.y;
  o4.z = (v.z - mean) * inv * w4.z + b4.z;
  o4.w = (v.w - mean) * inv * w4.w + b4.w;
  if (OBF) {
    ushort4 o;
    o.x = f2bf(o4.x); o.y = f2bf(o4.y); o.z = f2bf(o4.z); o.w = f2bf(o4.w);
    ((ushort4*)((unsigned short*)out + (size_t)row * CDIM))[tid] = o;
  } else {
    ((float4*)((float*)out + (size_t)row * CDIM))[tid] = o4;
  }
}

// ---------------- weight fp32 [K,N] -> bf16 W^T [N,K] ------------------------
__global__ __launch_bounds__(256) void convT(const float* __restrict__ W,
    unsigned short* __restrict__ Wt, int K, int N)
{
  __shared__ float tile[32][33];
  const int kt = blockIdx.y * 32, nt = blockIdx.x * 32;
  const int r = threadIdx.x >> 3;        // 0..31
  const int c = (threadIdx.x & 7) * 4;   // 0..28
  float4 v = *(const float4*)(W + (size_t)(kt + r) * N + nt + c);
  tile[r][c] = v.x; tile[r][c+1] = v.y; tile[r][c+2] = v.z; tile[r][c+3] = v.w;
  __syncthreads();
  ushort4 o;
  o.x = f2bf(tile[c+0][r]); o.y = f2bf(tile[c+1][r]);
  o.z = f2bf(tile[c+2][r]); o.w = f2bf(tile[c+3][r]);
  *(ushort4*)(Wt + (size_t)(nt + r) * K + kt + c) = o;
}

// ---------------- flat fp32 -> bf16 ------------------------------------------
__global__ void conv_flat(const float* __restrict__ in, unsigned short* __restrict__ out)
{
  int i = blockIdx.x * blockDim.x + threadIdx.x;
  float4 v = ((const float4*)in)[i];
  ushort4 o;
  o.x = f2bf(v.x); o.y = f2bf(v.y); o.z = f2bf(v.z); o.w = f2bf(v.w);
  ((ushort4*)out)[i] = o;
}

// ---------------- bf16 MFMA GEMM: C = A[M,K] @ B^T[N,K]^T --------------------
// 256x256 tile, BK=64, 512 threads = 8 waves (2M x 4N), per-wave 128x64 out.
// Double-buffered LDS (128 KiB), glds16 staging with read-side XOR swizzle
// byte ^= ((row&7)<<4) pre-applied to the GLOBAL source (LDS dest stays linear,
// rule: both-sides-or-neither). 4 phases per K-tile (one C-quadrant = 16 MFMA),
// prefetch for tile k+1 issued in phases 1-2, single vmcnt(0) at the phase-4
// boundary (>=2 phases after last issue). Raw s_barrier only in the loop.
// EPI: 0=+bias ; 1=+bias+residual(extra f32) ; 2=gelu(+bias) ; 3=+bias+pos(extra)
#define EPAD 68     // fp32 row stride in repack LDS
#define GTILE 65536 // bytes per dbuf slot: A 32K + B 32K
template<int EPI, int OBF>
__global__ __launch_bounds__(512, 2) void gemm_bf16(
    const unsigned short* __restrict__ A, const unsigned short* __restrict__ Bt,
    const float* __restrict__ bias, const float* __restrict__ extra,
    void* __restrict__ Cout, int M, int N, int K)
{
  __shared__ __align__(16) char smem[2 * GTILE];
  const int tid = threadIdx.x;
  const int wave = tid >> 6, lane = tid & 63;
  const int ln15 = lane & 15, quad = lane >> 4;

  // swizzle: groups of 8 m-tiles sweep all n-tiles (A slice stays in XCD L2)
  const int ntiles = N >> 8;
  const int per = ntiles << 3;
  const int g = blockIdx.x / per, rr = blockIdx.x % per;
  const int m0 = ((g << 3) + (rr & 7)) << 8;
  const int n0 = (rr >> 3) << 8;
  const int wm = (wave >> 2) * 128, wn = (wave & 3) * 64;

  // staging: A tile = 32 units of 8 rows x 128B; wave w takes units {s*8+w}.
  // lane covers row (lane>>3), 16B chunk (lane&7), with the read-side XOR
  // pre-applied to the SOURCE column so the glds16 LDS dest stays linear.
  const int srow = lane >> 3;
  const int scol = ((lane & 7) ^ srow) << 4;
  const size_t rs = (size_t)K * 2;
  const char* aSrc = (const char*)(A + (size_t)(m0 + wave * 8 + srow) * K) + scol;
  const char* bSrc = (const char*)(Bt + (size_t)(n0 + wave * 8 + srow) * K) + scol;
  const int sdst = wave * 1024;

  // read side: byte = row*128 + (col ^ ((row&7)<<4)); row&7 == ln15&7 here
  const int axor = (ln15 & 7) << 4;
  const int kq0 = (quad * 16) ^ axor;
  const int kq1 = (64 + quad * 16) ^ axor;
  const int aRd = (wm + ln15) * 128;
  const int bRd = (wn + ln15) * 128;

  f32x4 acc[8][4];
  #pragma unroll
  for (int i = 0; i < 8; ++i)
    #pragma unroll
    for (int j = 0; j < 4; ++j) acc[i][j] = (f32x4){0.f, 0.f, 0.f, 0.f};

  bf16x8 af[4][2];   // current mh half: [mf][ks]
  bf16x8 bfr[4][2];  // all four nf:     [nf][ks]

  #define STAGE_A(buf, kt2) { \
    const char* s_ = aSrc + (size_t)(kt2) * 128; \
    char* d_ = smem + (buf) * GTILE + sdst; \
    glds16(s_,             d_); \
    glds16(s_ +  64 * rs,  d_ + 8192); \
    glds16(s_ + 128 * rs,  d_ + 16384); \
    glds16(s_ + 192 * rs,  d_ + 24576); }
  #define STAGE_B(buf, kt2) { \
    const char* s_ = bSrc + (size_t)(kt2) * 128; \
    char* d_ = smem + (buf) * GTILE + 32768 + sdst; \
    glds16(s_,             d_); \
    glds16(s_ +  64 * rs,  d_ + 8192); \
    glds16(s_ + 128 * rs,  d_ + 16384); \
    glds16(s_ + 192 * rs,  d_ + 24576); }
  #define LDA(buf, mh) { \
    const char* p_ = smem + (buf) * GTILE + aRd + (mh) * 8192; \
    _Pragma("unroll") \
    for (int mf = 0; mf < 4; ++mf) { \
      af[mf][0] = *(const bf16x8*)(p_ + mf * 2048 + kq0); \
      af[mf][1] = *(const bf16x8*)(p_ + mf * 2048 + kq1); } }
  #define LDB(buf, nh) { \
    const char* p_ = smem + (buf) * GTILE + 32768 + bRd + (nh) * 4096; \
    _Pragma("unroll") \
    for (int nf = 0; nf < 2; ++nf) { \
      bfr[(nh)*2+nf][0] = *(const bf16x8*)(p_ + nf * 2048 + kq0); \
      bfr[(nh)*2+nf][1] = *(const bf16x8*)(p_ + nf * 2048 + kq1); } }
  #define MMA(mh, nh) { \
    _Pragma("unroll") \
    for (int mf = 0; mf < 4; ++mf) \
      _Pragma("unroll") \
      for (int nf = 0; nf < 2; ++nf) { \
        acc[(mh)*4+mf][(nh)*2+nf] = __builtin_amdgcn_mfma_f32_16x16x32_bf16( \
            af[mf][0], bfr[(nh)*2+nf][0], acc[(mh)*4+mf][(nh)*2+nf], 0, 0, 0); \
        acc[(mh)*4+mf][(nh)*2+nf] = __builtin_amdgcn_mfma_f32_16x16x32_bf16( \
            af[mf][1], bfr[(nh)*2+nf][1], acc[(mh)*4+mf][(nh)*2+nf], 0, 0, 0); } }
  // rule #18: sched_barrier after inline-asm lgkmcnt so MFMA isn't hoisted past it
  #define WAIT_LGKM do { asm volatile("s_waitcnt lgkmcnt(0)" ::: "memory"); \
                         __builtin_amdgcn_sched_barrier(0); } while (0)

  const int KT = K >> 6;
  STAGE_A(0, 0); STAGE_B(0, 0);
  asm volatile("s_waitcnt vmcnt(0)" ::: "memory");
  __builtin_amdgcn_s_barrier();

  int cur = 0;
  for (int kt = 0; kt < KT; ++kt) {
    const int nxt = cur ^ 1;
    const bool pf = (kt + 1 < KT);
    // ---- phase 1: quadrant (0,0); issue next-tile A prefetch
    LDA(cur, 0); LDB(cur, 0);
    if (pf) STAGE_A(nxt, kt + 1);
    __builtin_amdgcn_s_barrier();
    WAIT_LGKM;
    __builtin_amdgcn_s_setprio(1);
    MMA(0, 0);
    __builtin_amdgcn_s_setprio(0);
    __builtin_amdgcn_s_barrier();
    // ---- phase 2: quadrant (0,1); issue next-tile B prefetch
    LDB(cur, 1);
    if (pf) STAGE_B(nxt, kt + 1);
    __builtin_amdgcn_s_barrier();
    WAIT_LGKM;
    __builtin_amdgcn_s_setprio(1);
    MMA(0, 1);
    __builtin_amdgcn_s_setprio(0);
    __builtin_amdgcn_s_barrier();
    // ---- phase 3: quadrant (1,0)
    LDA(cur, 1);
    __builtin_amdgcn_s_barrier();
    WAIT_LGKM;
    __builtin_amdgcn_s_setprio(1);
    MMA(1, 0);
    __builtin_amdgcn_s_setprio(0);
    __builtin_amdgcn_s_barrier();
    // ---- phase 4: quadrant (1,1); drain prefetch before buffer swap
    __builtin_amdgcn_s_setprio(1);
    MMA(1, 1);
    __builtin_amdgcn_s_setprio(0);
    asm volatile("s_waitcnt vmcnt(0)" ::: "memory");
    __builtin_amdgcn_s_barrier();
    cur = nxt;
  }

  // ---- epilogue via per-wave LDS repack (aliases tile LDS; barrier first) ----
  __builtin_amdgcn_s_barrier();
  float* ep = (float*)smem + wave * 16 * EPAD;
  const int cl = ln15, rq = quad * 4;
  #pragma unroll
  for (int i = 0; i < 8; ++i) {
    #pragma unroll
    for (int j = 0; j < 4; ++j) {
      const float bj = bias[n0 + wn + j * 16 + cl];
      #pragma unroll
      for (int r = 0; r < 4; ++r) {
        float val = acc[i][j][r] + bj;
        if (EPI == 2) val = gelu_fast(val);
        if (OBF) ((unsigned short*)ep)[(rq + r) * (2 * EPAD) + j * 16 + cl] = f2bf(val);
        else     ep[(rq + r) * EPAD + j * 16 + cl] = val;
      }
    }
    const int mbase = m0 + wm + i * 16;
    if (OBF) {
      #pragma unroll
      for (int s = 0; s < 2; ++s) {
        int f = s * 64 + lane;
        int row = f >> 3, ch = f & 7;
        uint4 v = *(const uint4*)((const unsigned short*)ep + row * (2 * EPAD) + ch * 8);
        *(uint4*)((unsigned short*)Cout + (size_t)(mbase + row) * N + n0 + wn + ch * 8) = v;
      }
    } else {
      #pragma unroll
      for (int s = 0; s < 4; ++s) {
        int f = s * 64 + lane;
        int row = f >> 4, ch = f & 15;
        float4 v = *(const float4*)(ep + row * EPAD + ch * 4);
        const int m = mbase + row;
        const size_t off = (size_t)m * N + n0 + wn + ch * 4;
        if (EPI == 1) {
          float4 e = *(const float4*)(extra + off);
          v.x += e.x; v.y += e.y; v.z += e.z; v.w += e.w;
        } else if (EPI == 3) {
          float4 e = *(const float4*)(extra + (size_t)(m & (T_SEQ - 1)) * N + n0 + wn + ch * 4);
          v.x += e.x; v.y += e.y; v.z += e.z; v.w += e.w;
        }
        *(float4*)((float*)Cout + off) = v;
      }
    }
  }
  #undef STAGE_A
  #undef STAGE_B
  #undef LDA
  #undef LDB
  #undef MMA
  #undef WAIT_LGKM
}

// ---------------- fp32 GEMM (kept for tiny actor head) -----------------------
template<int EPI>
__global__ __launch_bounds__(256) void gemm_f32(const float* __restrict__ A,
    const float* __restrict__ B, const float* __restrict__ bias,
    const float* __restrict__ extra, float* __restrict__ C,
    int M, int N, int K)
{
  __shared__ float As[16][64];
  __shared__ float Bs[16][64];
  const int tid = threadIdx.x;
  const int m0 = blockIdx.x * 64, n0 = blockIdx.y * 64;
  const int tx = tid & 15, ty = tid >> 4;
  const int ar = tid >> 2, ak = (tid & 3) * 4;
  const int br = tid >> 4, bc = (tid & 15) * 4;
  const float* Ap = A + (size_t)(m0 + ar) * K + ak;
  const float* Bp = B + (size_t)br * N + n0 + bc;
  float acc[4][4] = {};
  for (int k0 = 0; k0 < K; k0 += 16) {
    float4 av = *(const float4*)(Ap + k0);
    float4 bv = *(const float4*)(Bp + (size_t)k0 * N);
    __syncthreads();
    As[ak+0][ar] = av.x; As[ak+1][ar] = av.y; As[ak+2][ar] = av.z; As[ak+3][ar] = av.w;
    *(float4*)&Bs[br][bc] = bv;
    __syncthreads();
    #pragma unroll
    for (int k = 0; k < 16; ++k) {
      float4 a4 = *(const float4*)&As[k][ty * 4];
      float4 b4 = *(const float4*)&Bs[k][tx * 4];
      float avv[4] = {a4.x, a4.y, a4.z, a4.w};
      float bvv[4] = {b4.x, b4.y, b4.z, b4.w};
      #pragma unroll
      for (int i = 0; i < 4; ++i)
        #pragma unroll
        for (int j = 0; j < 4; ++j)
          acc[i][j] = fmaf(avv[i], bvv[j], acc[i][j]);
    }
  }
  float4 bi = *(const float4*)(bias + n0 + tx * 4);
  #pragma unroll
  for (int i = 0; i < 4; ++i) {
    int m = m0 + ty * 4 + i;
    size_t off = (size_t)m * N + n0 + tx * 4;
    float4 r;
    r.x = acc[i][0] + bi.x; r.y = acc[i][1] + bi.y;
    r.z = acc[i][2] + bi.z; r.w = acc[i][3] + bi.w;
    if (EPI == 1) {
      float4 rs = *(const float4*)(extra + off);
      r.x += rs.x; r.y += rs.y; r.z += rs.z; r.w += rs.w;
    }
    *(float4*)(C + off) = r;
  }
}

// ---------------- bucketed local attention via MFMA ---------------------------
#define ATT_KP 72    // Kb row stride (elems): 64 + 8 pad, keeps 16B align
#define ATT_VP 136   // Vt/Pb row stride (elems): 128 + 8 pad
__global__ __launch_bounds__(256) void attn_mfma(const unsigned short* __restrict__ qkv,
    unsigned short* __restrict__ out)
{
  __shared__ __align__(16) unsigned short Kb[128 * ATT_KP];  // K rows [j][d]
  __shared__ __align__(16) unsigned short Vt[64 * ATT_VP];   // V^T [d][j]
  __shared__ __align__(16) unsigned short Pb[64 * ATT_VP];   // P [i][j] A-layout
  const int n = blockIdx.x, h = blockIdx.y, b = blockIdx.z;
  const int tid = threadIdx.x;
  const int wave = tid >> 6, lane = tid & 63;
  const int ln15 = lane & 15, quad = lane >> 4;
  const int C3 = 3 * CDIM;
  const size_t bbase = (size_t)b * T_SEQ * C3;
  const int kcol = CDIM + h * HDIM, vcol = 2 * CDIM + h * HDIM;

  #pragma unroll
  for (int i = 0; i < 4; ++i) {
    int idx = tid + 256 * i;
    int j = idx >> 3, d8 = (idx & 7) * 8;
    uint4 r = make_uint4(0u, 0u, 0u, 0u);
    if (j >= 64 || n > 0) {
      int t = (j >= 64) ? (n * BSZ + j - 64) : ((n - 1) * BSZ + j);
      r = *(const uint4*)(qkv + bbase + (size_t)t * C3 + kcol + d8);
    }
    *(uint4*)&Kb[j * ATT_KP + d8] = r;
  }
  #pragma unroll
  for (int i = 0; i < 16; ++i) {
    int idx = tid + 256 * i;
    int j = idx >> 5, d2 = (idx & 31) * 2;
    unsigned int r = 0u;
    if (j >= 64 || n > 0) {
      int t = (j >= 64) ? (n * BSZ + j - 64) : ((n - 1) * BSZ + j);
      r = *(const unsigned int*)(qkv + bbase + (size_t)t * C3 + vcol + d2);
    }
    Vt[d2 * ATT_VP + j]       = (unsigned short)(r & 0xffffu);
    Vt[(d2 + 1) * ATT_VP + j] = (unsigned short)(r >> 16);
  }
  const int it = wave;
  const int qm = n * BSZ + it * 16 + ln15;
  bf16x8 aq[2];
  #pragma unroll
  for (int ks = 0; ks < 2; ++ks)
    aq[ks] = *(const bf16x8*)(qkv + bbase + (size_t)qm * C3 + h * HDIM + ks * 32 + quad * 8);
  __syncthreads();

  f32x4 accs[8];
  #pragma unroll
  for (int jt = 0; jt < 8; ++jt) accs[jt] = (f32x4){0.f, 0.f, 0.f, 0.f};
  #pragma unroll
  for (int jt = 0; jt < 8; ++jt)
    #pragma unroll
    for (int ks = 0; ks < 2; ++ks) {
      bf16x8 bk = *(const bf16x8*)&Kb[(jt * 16 + ln15) * ATT_KP + ks * 32 + quad * 8];
      accs[jt] = __builtin_amdgcn_mfma_f32_16x16x32_bf16(aq[ks], bk, accs[jt], 0, 0, 0);
    }

  #pragma unroll
  for (int r = 0; r < 4; ++r) {
    const int irow = it * 16 + quad * 4 + r;
    float p8[8];
    float mx = -1e30f;
    #pragma unroll
    for (int jt = 0; jt < 8; ++jt) {
      int j = jt * 16 + ln15;
      float s = accs[jt][r] * 0.125f;
      bool ok = (j < BSZ) || (j - BSZ <= irow);
      s = ok ? s : -1e30f;
      p8[jt] = s;
      mx = fmaxf(mx, s);
    }
    mx = fmaxf(mx, __shfl_xor(mx, 1));
    mx = fmaxf(mx, __shfl_xor(mx, 2));
    mx = fmaxf(mx, __shfl_xor(mx, 4));
    mx = fmaxf(mx, __shfl_xor(mx, 8));
    float l = 0.f;
    #pragma unroll
    for (int jt = 0; jt < 8; ++jt) { float e = __expf(p8[jt] - mx); p8[jt] = e; l += e; }
    l += __shfl_xor(l, 1); l += __shfl_xor(l, 2);
    l += __shfl_xor(l, 4); l += __shfl_xor(l, 8);
    const float linv = 1.0f / l;
    #pragma unroll
    for (int jt = 0; jt < 8; ++jt)
      Pb[irow * ATT_VP + jt * 16 + ln15] = f2bf(p8[jt] * linv);
  }

  f32x4 acco[4];
  #pragma unroll
  for (int dt = 0; dt < 4; ++dt) acco[dt] = (f32x4){0.f, 0.f, 0.f, 0.f};
  #pragma unroll
  for (int ks = 0; ks < 4; ++ks) {
    bf16x8 pa = *(const bf16x8*)&Pb[(it * 16 + ln15) * ATT_VP + ks * 32 + quad * 8];
    #pragma unroll
    for (int dt = 0; dt < 4; ++dt) {
      bf16x8 bv = *(const bf16x8*)&Vt[(dt * 16 + ln15) * ATT_VP + ks * 32 + quad * 8];
      acco[dt] = __builtin_amdgcn_mfma_f32_16x16x32_bf16(pa, bv, acco[dt], 0, 0, 0);
    }
  }

  unsigned short* op = out + (size_t)(b * T_SEQ + n * BSZ) * CDIM + h * HDIM;
  #pragma unroll
  for (int dt = 0; dt < 4; ++dt)
    #pragma unroll
    for (int r = 0; r < 4; ++r)
      op[(size_t)(it * 16 + quad * 4 + r) * CDIM + dt * 16 + ln15] = f2bf(acco[dt][r]);
}

// ---------------- critic head ------------------------------------------------
__global__ __launch_bounds__(256) void critic_kernel(const float* __restrict__ x,
    const float* __restrict__ w, const float* __restrict__ b, float* __restrict__ out)
{
  int row = blockIdx.x * 4 + (threadIdx.x >> 6);
  int lane = threadIdx.x & 63;
  const float* xr = x + (size_t)row * CDIM;
  float s = 0.f;
  #pragma unroll
  for (int i = 0; i < 16; ++i) s = fmaf(xr[lane + 64*i], w[lane + 64*i], s);
  #pragma unroll
  for (int o = 32; o > 0; o >>= 1) s += __shfl_down(s, o);
  if (lane == 0) out[row] = s + b[0];
}

__global__ void copy64_kernel(const float* __restrict__ in, float* __restrict__ out)
{
  out[threadIdx.x] = in[threadIdx.x];
}

// -----------------------------------------------------------------------------
extern "C" void kernel_launch(void* const* d_in, const int* in_sizes, int n_in,
                              void* d_out, int out_size, void* d_ws, size_t ws_size,
                              hipStream_t stream)
{
  const float* states   = (const float*)d_in[0];
  const float* emb_w    = (const float*)d_in[1];
  const float* emb_b    = (const float*)d_in[2];
  const float* pos      = (const float*)d_in[3];
  const float* ln1_w    = (const float*)d_in[4];
  const float* ln1_b    = (const float*)d_in[5];
  const float* qkv_w    = (const float*)d_in[6];
  const float* qkv_b    = (const float*)d_in[7];
  const float* ow       = (const float*)d_in[8];
  const float* obs      = (const float*)d_in[9];
  const float* ln2_w    = (const float*)d_in[10];
  const float* ln2_b    = (const float*)d_in[11];
  const float* w1       = (const float*)d_in[12];
  const float* b1       = (const float*)d_in[13];
  const float* w2       = (const float*)d_in[14];
  const float* b2       = (const float*)d_in[15];
  const float* lnf_w    = (const float*)d_in[16];
  const float* lnf_b    = (const float*)d_in[17];
  const float* actor_w  = (const float*)d_in[18];
  const float* actor_b  = (const float*)d_in[19];
  const float* logstd   = (const float*)d_in[20];
  const float* critic_w = (const float*)d_in[21];
  const float* critic_b = (const float*)d_in[22];

  char* wsb = (char*)d_ws;
  float* x              = (float*)wsb;
  unsigned short* qkvb  = (unsigned short*)(wsb + (64ull  << 20));
  float* hbuf           = (float*)(wsb + (64ull << 20));
  unsigned short* lnb   = (unsigned short*)(wsb + (160ull << 20));
  unsigned short* mlpb  = (unsigned short*)(wsb + (192ull << 20));
  unsigned short* statesb = mlpb;
  unsigned short* wq    = (unsigned short*)(wsb + (320ull << 20));
  unsigned short* wo    = wq  + (size_t)3072 * 1024;
  unsigned short* wm1   = wo  + (size_t)1024 * 1024;
  unsigned short* wm2   = wm1 + (size_t)4096 * 1024;
  unsigned short* wemb  = wm2 + (size_t)1024 * 4096;

  float* logits     = (float*)d_out;
  float* out_logstd = logits + (size_t)MROWS * 64;
  float* out_values = out_logstd + 64;

  dim3 blk(256);
  dim3 gblk(512);

  conv_flat<<<4096, blk, 0, stream>>>(states, statesb);
  convT<<<dim3(1024/32, 256/32), blk, 0, stream>>>(emb_w, wemb, 256, 1024);
  // 64 m-tiles x (N/256) n-tiles
  gemm_bf16<3,0><<<dim3(64 * 4), gblk, 0, stream>>>(
      statesb, wemb, emb_b, pos, x, MROWS, CDIM, 256);

  for (int l = 0; l < NL; ++l) {
    convT<<<dim3(3072/32, 1024/32), blk, 0, stream>>>(qkv_w + (size_t)l*CDIM*3*CDIM, wq,  1024, 3072);
    convT<<<dim3(1024/32, 1024/32), blk, 0, stream>>>(ow    + (size_t)l*CDIM*CDIM,   wo,  1024, 1024);
    convT<<<dim3(4096/32, 1024/32), blk, 0, stream>>>(w1    + (size_t)l*CDIM*4*CDIM, wm1, 1024, 4096);
    convT<<<dim3(1024/32, 4096/32), blk, 0, stream>>>(w2    + (size_t)l*4*CDIM*CDIM, wm2, 4096, 1024);

    ln_kernel<1><<<MROWS, blk, 0, stream>>>(x, ln1_w + l*CDIM, ln1_b + l*CDIM, lnb);
    gemm_bf16<0,1><<<dim3(64 * 12), gblk, 0, stream>>>(
        lnb, wq, qkv_b + (size_t)l*3*CDIM, nullptr, qkvb, MROWS, 3*CDIM, CDIM);
    attn_mfma<<<dim3(T_SEQ/BSZ, NH, 4), blk, 0, stream>>>(qkvb, lnb);
    gemm_bf16<1,0><<<dim3(64 * 4), gblk, 0, stream>>>(
        lnb, wo, obs + (size_t)l*CDIM, x, x, MROWS, CDIM, CDIM);
    ln_kernel<1><<<MROWS, blk, 0, stream>>>(x, ln2_w + l*CDIM, ln2_b + l*CDIM, lnb);
    gemm_bf16<2,1><<<dim3(64 * 16), gblk, 0, stream>>>(
        lnb, wm1, b1 + (size_t)l*4*CDIM, nullptr, mlpb, MROWS, 4*CDIM, CDIM);
    gemm_bf16<1,0><<<dim3(64 * 4), gblk, 0, stream>>>(
        mlpb, wm2, b2 + (size_t)l*CDIM, x, x, MROWS, CDIM, 4*CDIM);
  }

  ln_kernel<0><<<MROWS, blk, 0, stream>>>(x, lnf_w, lnf_b, hbuf);
  gemm_f32<0><<<dim3(MROWS/64, 1), blk, 0, stream>>>(
      hbuf, actor_w, actor_b, nullptr, logits, MROWS, 64, CDIM);
  critic_kernel<<<MROWS/4, blk, 0, stream>>>(hbuf, critic_w, critic_b, out_values);
  copy64_kernel<<<1, 64, 0, stream>>>(logstd, out_logstd);
}